// Round 4
// baseline (5596.127 us; speedup 1.0000x reference)
//
#include <hip/hip_runtime.h>
#include <hip/hip_fp16.h>

#define NDIM 92
#define HDIM 64
#define EDIM 41
#define ZC   128   // 2H
#define CIN  169   // 2H + EDIM
#define NB   2048  // pass-A grid / stats partial rows

typedef __attribute__((ext_vector_type(8))) short short8;   // 8 bf16 (4 VGPR)
typedef __attribute__((ext_vector_type(4))) float f32x4;

static __device__ inline unsigned short f2bf(float x) {
    unsigned u = __float_as_uint(x);
    unsigned r = (u + 0x7FFF + ((u >> 16) & 1)) >> 16;   // RNE
    return (unsigned short)r;
}

// ---------------------------------------------------------------- embedding
__global__ __launch_bounds__(256) void k_embed(
    const float* __restrict__ nf, const float* __restrict__ W,
    const float* __restrict__ b, float* __restrict__ h, int N)
{
    __shared__ float Wl[NDIM * HDIM];
    __shared__ float nfl[4][NDIM];
    int t = threadIdx.x;
    for (int i = t; i < NDIM * HDIM; i += 256) Wl[i] = W[i];
    int n0 = blockIdx.x * 4;
    for (int i = t; i < 4 * NDIM; i += 256) {
        int slot = i / NDIM, k = i - slot * NDIM;
        int n = n0 + slot;
        nfl[slot][k] = (n < N) ? nf[n * NDIM + k] : 0.f;
    }
    __syncthreads();
    int j = t & 63, slot = t >> 6;
    int n = n0 + slot;
    if (n >= N) return;
    float acc = b[j];
    #pragma unroll
    for (int k = 0; k < NDIM; k++) acc += nfl[slot][k] * Wl[k * HDIM + j];
    h[n * HDIM + j] = acc;
}

// ---------------------------------------------------------------- node GEMM
__global__ __launch_bounds__(256) void k_pq(
    const float* __restrict__ h, const float* __restrict__ Wl,
    float* __restrict__ PQ, int N)
{
    __shared__ float Wcat[64 * 256];
    __shared__ float hl[32 * 64];
    int t = threadIdx.x;
    for (int i = t; i < 64 * 256; i += 256) {
        int k = i >> 8, c = i & 255;
        Wcat[i] = (c < 128) ? Wl[k * 128 + c] : Wl[(64 + k) * 128 + (c - 128)];
    }
    int jg = t & 63, w = t >> 6;
    int ntiles = (N + 31) >> 5;
    for (int tile = blockIdx.x; tile < ntiles; tile += gridDim.x) {
        int nbase = tile << 5;
        __syncthreads();
        for (int i = t; i < 32 * 64; i += 256) {
            int nn = nbase + (i >> 6);
            hl[i] = (nn < N) ? h[nn * 64 + (i & 63)] : 0.f;
        }
        __syncthreads();
        float acc[8][4];
        #pragma unroll
        for (int n = 0; n < 8; n++)
            acc[n][0] = acc[n][1] = acc[n][2] = acc[n][3] = 0.f;
        for (int k = 0; k < 64; k++) {
            float4 w4 = *(const float4*)&Wcat[k * 256 + jg * 4];
            #pragma unroll
            for (int n = 0; n < 8; n++) {
                float hv = hl[(w * 8 + n) * 64 + k];
                acc[n][0] += hv * w4.x; acc[n][1] += hv * w4.y;
                acc[n][2] += hv * w4.z; acc[n][3] += hv * w4.w;
            }
        }
        #pragma unroll
        for (int n = 0; n < 8; n++) {
            int nn = nbase + w * 8 + n;
            if (nn < N)
                *(float4*)&PQ[nn * 256 + jg * 4] =
                    make_float4(acc[n][0], acc[n][1], acc[n][2], acc[n][3]);
        }
    }
}

// ---------------------------------------------------------------- Wbot swizzle
// Wsw[((ks*8+nt)*64+lane)*8 + i] = bf16( Wbot[k][n] ), k=ks*32+(lane>>4)*8+i,
// n=nt*16+(lane&15); zero for k>=41.
__global__ __launch_bounds__(64) void k_wswz(
    const float* __restrict__ Wl, unsigned short* __restrict__ Wsw)
{
    int b = blockIdx.x;            // 16 blocks: ks = b>>3, nt = b&7
    int ks = b >> 3, nt = b & 7;
    int lane = threadIdx.x;
    #pragma unroll
    for (int i = 0; i < 8; i++) {
        int k = ks * 32 + ((lane >> 4) * 8) + i;
        int n = nt * 16 + (lane & 15);
        float v = (k < EDIM) ? Wl[(128 + k) * 128 + n] : 0.f;
        Wsw[((size_t)(ks * 8 + nt) * 64 + lane) * 8 + i] = f2bf(v);
    }
}

// ---------------------------------------------------------------- pass A (v4)
// Tile: 64 edges x 128 cols. MFMA for ef@Wbot (K padded to 64), C -> LDS fp16,
// then column-per-thread epilogue adds PQ gathers + bias, writes zh, stats.
// v4 fix: staging covers FULL k in [0,64) with explicit zeros (k>=41 and
// e>=E rows) — v3 left shorts [48,64) as uninitialized LDS; Inf*0=NaN through
// the MFMA accumulator poisoned valid rows.
__global__ __launch_bounds__(256) void k_passA(
    const float* __restrict__ PQ, const float* __restrict__ ef,
    const int* __restrict__ src, const int* __restrict__ dst,
    const unsigned short* __restrict__ Wsw, const float* __restrict__ bias,
    __half* __restrict__ zh, float* __restrict__ partials, int E)
{
    __shared__ unsigned short efl[64 * 72];   // bf16, row stride 72 (bank-safe)
    __shared__ __half Rl[64 * 128];           // MFMA result, fp16
    __shared__ float red[512];

    int t = threadIdx.x;
    int lane = t & 63;
    int w = t >> 6;           // wave id: edge group [w*16, w*16+16)
    int jcol = t & 127;       // epilogue column
    int slot = t >> 7;        // epilogue edge slot (0/1)

    // B-fragments resident in VGPRs for block lifetime (16 x 4 VGPR)
    short8 bfr[2][8];
    #pragma unroll
    for (int ks = 0; ks < 2; ks++)
        #pragma unroll
        for (int nt = 0; nt < 8; nt++)
            bfr[ks][nt] = *(const short8*)(Wsw + ((size_t)(ks * 8 + nt) * 64 + lane) * 8);

    float bj = bias[jcol];
    float psum = 0.f, psq = 0.f;

    int arow = (w * 16 + (lane & 15));            // A-frag edge row in tile
    int aq   = (lane >> 4) * 8;                   // A-frag k sub-offset
    int crow = w * 16 + (lane >> 4) * 4;          // C rows base (reg adds 0..3)
    int ccol = lane & 15;                         // C col base within nt tile

    int ntiles = (E + 63) >> 6;
    for (int tile = blockIdx.x; tile < ntiles; tile += gridDim.x) {
        int e0 = tile << 6;
        __syncthreads();
        // ---- stage ef tile: fp32 -> bf16, 64 rows x 32 uint-packs (k [0,64))
        #pragma unroll
        for (int s = 0; s < 8; s++) {
            int idx = s * 256 + t;                // 2048 packs
            int row = idx >> 5, q = idx & 31;
            int e = e0 + row;
            int k0 = q * 2;
            unsigned pack = 0;
            if (e < E) {
                float v0 = (k0 < EDIM) ? ef[(size_t)e * EDIM + k0] : 0.f;
                float v1 = (k0 + 1 < EDIM) ? ef[(size_t)e * EDIM + k0 + 1] : 0.f;
                pack = (unsigned)f2bf(v0) | ((unsigned)f2bf(v1) << 16);
            }
            ((unsigned*)efl)[row * 36 + q] = pack;
        }
        __syncthreads();
        // ---- MFMA: 16 edges x 128 cols per wave, K = 64 (zeros beyond 41)
        {
            short8 a0 = *(const short8*)(efl + arow * 72 + aq);       // k [0,32)
            short8 a1 = *(const short8*)(efl + arow * 72 + 32 + aq);  // k [32,64)
            f32x4 acc[8];
            #pragma unroll
            for (int nt = 0; nt < 8; nt++) {
                acc[nt] = (f32x4){0.f, 0.f, 0.f, 0.f};
                acc[nt] = __builtin_amdgcn_mfma_f32_16x16x32_bf16(a0, bfr[0][nt], acc[nt], 0, 0, 0);
                acc[nt] = __builtin_amdgcn_mfma_f32_16x16x32_bf16(a1, bfr[1][nt], acc[nt], 0, 0, 0);
            }
            #pragma unroll
            for (int nt = 0; nt < 8; nt++)
                #pragma unroll
                for (int r = 0; r < 4; r++)
                    Rl[(crow + r) * 128 + nt * 16 + ccol] = __float2half(acc[nt][r]);
        }
        __syncthreads();
        // ---- epilogue: z = R + PQ[src][j] + PQ[dst][128+j] + b; stats; store
        #pragma unroll
        for (int i2 = 0; i2 < 64; i2 += 8) {
            #pragma unroll
            for (int u = 0; u < 4; u++) {
                int el = i2 + u * 2 + slot;
                int e = e0 + el;
                if (e < E) {
                    int s = src[e], d = dst[e];           // wave-uniform -> s_load
                    float z = __half2float(Rl[el * 128 + jcol])
                            + PQ[(size_t)s * 256 + jcol]
                            + PQ[(size_t)d * 256 + 128 + jcol] + bj;
                    zh[(size_t)e * 128 + jcol] = __float2half(z);
                    psum += z; psq += z * z;
                }
            }
        }
    }
    red[t] = psum; red[256 + t] = psq;
    __syncthreads();
    if (t < 128) {
        partials[blockIdx.x * 256 + t]       = red[t] + red[t + 128];
        partials[blockIdx.x * 256 + 128 + t] = red[256 + t] + red[256 + t + 128];
    }
}

// ---------------------------------------------------------------- stats
__global__ __launch_bounds__(256) void k_red1(
    const float* __restrict__ partials, float* __restrict__ p2, int nb)
{
    int t = threadIdx.x, r = blockIdx.x;
    float s = 0.f;
    int b0 = r * 32, b1 = b0 + 32; if (b1 > nb) b1 = nb;
    for (int b = b0; b < b1; b++) s += partials[b * 256 + t];
    p2[r * 256 + t] = s;
}

__global__ __launch_bounds__(256) void k_bnstats(
    const float* __restrict__ p2, const float* __restrict__ gamma,
    const float* __restrict__ beta, float* __restrict__ bnA,
    float* __restrict__ bnC, int R, float invE)
{
    int t = threadIdx.x;
    float s = 0.f;
    for (int r = 0; r < R; r++) s += p2[r * 256 + t];
    __shared__ float red[256];
    red[t] = s;
    __syncthreads();
    if (t < 128) {
        float mean = red[t] * invE;
        float var  = red[128 + t] * invE - mean * mean;
        float a = gamma[t] * rsqrtf(var + 1e-5f);
        bnA[t] = a;
        bnC[t] = beta[t] - mean * a;
    }
}

// ---------------------------------------------------------------- pass B
__global__ __launch_bounds__(256) void k_passB(
    const __half* __restrict__ zh, const int* __restrict__ src,
    const float* __restrict__ bnA, const float* __restrict__ bnC,
    float* __restrict__ h, int E)
{
    int t = threadIdx.x;
    int j = t & 63, slot = t >> 6;
    float a0 = bnA[j],      c0 = bnC[j];
    float a1 = bnA[64 + j], c1 = bnC[64 + j];
    for (int e = blockIdx.x * 4 + slot; e < E; e += gridDim.x * 4) {
        float za = __half2float(zh[(size_t)e * 128 + j])      * a0 + c0;
        float zb = __half2float(zh[(size_t)e * 128 + 64 + j]) * a1 + c1;
        float sig = 1.f / (1.f + __expf(-za));
        float sp  = fmaxf(zb, 0.f) + log1pf(__expf(-fabsf(zb)));
        atomicAdd(&h[(size_t)src[e] * 64 + j], sig * sp);
    }
}

// ---------------------------------------------------------------- pooling
__global__ __launch_bounds__(256) void k_pool(
    const float* __restrict__ h, const int* __restrict__ gid,
    float* __restrict__ pool, float* __restrict__ cnt, int N)
{
    int t = threadIdx.x;
    int j = t & 63, slot = t >> 6;
    int n = blockIdx.x * 4 + slot;
    if (n >= N) return;
    int g = gid[n];
    atomicAdd(&pool[g * 64 + j], h[n * 64 + j]);
    if (j == 0) atomicAdd(&cnt[g], 1.f);
}

// ---------------------------------------------------------------- head
__global__ __launch_bounds__(128) void k_head(
    const float* __restrict__ pool, const float* __restrict__ cnt,
    const float* __restrict__ fcW, const float* __restrict__ fcb,
    const float* __restrict__ outW, const float* __restrict__ outb,
    float* __restrict__ out, int G)
{
    int g = blockIdx.x, t = threadIdx.x;
    __shared__ float pl[64];
    if (t < 64) pl[t] = pool[g * 64 + t] / fmaxf(cnt[g], 1.f);
    __syncthreads();
    float acc = fcb[t];
    #pragma unroll
    for (int k = 0; k < 64; k++) acc += pl[k] * fcW[k * 128 + t];
    float sp = fmaxf(acc, 0.f) + log1pf(__expf(-fabsf(acc)));
    float v = sp * outW[t];
    __shared__ float red[128];
    red[t] = v;
    __syncthreads();
    for (int s = 64; s > 0; s >>= 1) {
        if (t < s) red[t] += red[t + s];
        __syncthreads();
    }
    if (t == 0) out[g] = red[0] + outb[0];
}

// ---------------------------------------------------------------- launcher
extern "C" void kernel_launch(void* const* d_in, const int* in_sizes, int n_in,
                              void* d_out, int out_size, void* d_ws, size_t ws_size,
                              hipStream_t stream)
{
    const float* nf    = (const float*)d_in[0];
    const int*   ei    = (const int*)d_in[1];
    const float* ef    = (const float*)d_in[2];
    const int*   gid   = (const int*)d_in[3];
    const float* embW  = (const float*)d_in[4];
    const float* embB  = (const float*)d_in[5];
    const float* convW = (const float*)d_in[6];
    const float* convB = (const float*)d_in[7];
    const float* gam   = (const float*)d_in[8];
    const float* bet   = (const float*)d_in[9];
    const float* fcW   = (const float*)d_in[10];
    const float* fcb   = (const float*)d_in[11];
    const float* outW  = (const float*)d_in[12];
    const float* outb  = (const float*)d_in[13];
    float* out = (float*)d_out;

    int N = in_sizes[0] / NDIM;
    int E = in_sizes[1] / 2;
    int G = out_size;
    const int* src = ei;
    const int* dst = ei + E;

    char* ws = (char*)d_ws;
    size_t off = 0;
    auto alloc = [&](size_t bytes) {
        void* p = ws + off;
        off = (off + bytes + 255) & ~(size_t)255;
        return p;
    };
    float*  h        = (float*)alloc((size_t)N * 64 * 4);
    float*  PQ       = (float*)alloc((size_t)N * 256 * 4);
    __half* zh       = (__half*)alloc((size_t)E * 128 * 2);
    float*  partials = (float*)alloc((size_t)NB * 256 * 4);
    float*  p2       = (float*)alloc((size_t)64 * 256 * 4);
    float*  bnA      = (float*)alloc(128 * 4);
    float*  bnC      = (float*)alloc(128 * 4);
    unsigned short* Wsw = (unsigned short*)alloc(16384);
    float*  pool     = (float*)alloc((size_t)G * 65 * 4);
    float*  cnt      = pool + (size_t)G * 64;

    k_embed<<<(N + 3) / 4, 256, 0, stream>>>(nf, embW, embB, h, N);

    for (int l = 0; l < 3; l++) {
        const float* Wl = convW + (size_t)l * CIN * ZC;
        k_pq<<<1024, 256, 0, stream>>>(h, Wl, PQ, N);
        k_wswz<<<16, 64, 0, stream>>>(Wl, Wsw);
        k_passA<<<NB, 256, 0, stream>>>(PQ, ef, src, dst, Wsw, convB + l * ZC,
                                        zh, partials, E);
        k_red1<<<64, 256, 0, stream>>>(partials, p2, NB);
        k_bnstats<<<1, 256, 0, stream>>>(p2, gam + l * ZC, bet + l * ZC,
                                         bnA, bnC, 64, 1.f / (float)E);
        k_passB<<<4096, 256, 0, stream>>>(zh, src, bnA, bnC, h, E);
    }

    hipMemsetAsync(pool, 0, (size_t)G * 65 * 4, stream);
    k_pool<<<(N + 3) / 4, 256, 0, stream>>>(h, gid, pool, cnt, N);
    k_head<<<G, 128, 0, stream>>>(pool, cnt, fcW, fcb, outW, outb, out, G);
}